// Round 1
// baseline (1393.479 us; speedup 1.0000x reference)
//
#include <hip/hip_runtime.h>
#include <hip/hip_bf16.h>

// Problem constants (AKT core): B=16, S=512, D=512, H=8, DFF=2048, NB=2, L=6
#define Bsz  16
#define Sl   512
#define Dm   512
#define Hn   8
#define DKh  64
#define DFFn 2048
#define MROWS (Bsz * Sl)      // 8192
#define NEGV (-1e32f)

typedef _Float16 f16;
typedef f16 f16x8 __attribute__((ext_vector_type(8)));
typedef f16 f16x4 __attribute__((ext_vector_type(4)));
typedef float f32x4 __attribute__((ext_vector_type(4)));

// async global->LDS, 16B per lane: lds dst = wave-uniform base + lane*16
#define GLDS16(g, l) __builtin_amdgcn_global_load_lds( \
    (const __attribute__((address_space(1))) void*)(g), \
    (__attribute__((address_space(3))) void*)(l), 16, 0, 0)

// ---------------------------------------------------------------------------
// copies
// ---------------------------------------------------------------------------
__global__ void k_copy2(const float* __restrict__ in, float* __restrict__ out,
                        f16* __restrict__ outh, int n) {
    int i = blockIdx.x * 256 + threadIdx.x;
    if (i < n) { float v = in[i]; out[i] = v; outh[i] = (f16)v; }
}

// ---------------------------------------------------------------------------
// Weight convert+transpose: W[K,N] f32 -> Wt[N,K] f16 (per layer slice z).
// lmap=1 maps output slot z -> source layer {0,1,3,5}.
// ---------------------------------------------------------------------------
__global__ __launch_bounds__(256) void k_wconv(const float* __restrict__ src,
        f16* __restrict__ dst, int K, int N, int lmap)
{
    __shared__ float T[32][36];
    int z = blockIdx.z;
    int ls = lmap ? (z < 2 ? z : 2 * z - 1) : z;
    const float* S = src + (size_t)ls * K * N;
    f16* Dt = dst + (size_t)z * K * N;
    int n0 = blockIdx.x * 32, k0 = blockIdx.y * 32;
    int t = threadIdx.x;
    int r = t >> 3, c = (t & 7) * 4;
    float4 v = *(const float4*)(S + (size_t)(k0 + r) * N + n0 + c);
    T[r][c] = v.x; T[r][c + 1] = v.y; T[r][c + 2] = v.z; T[r][c + 3] = v.w;
    __syncthreads();
    int n = t >> 3, kq = (t & 7) * 4;
    f16x4 o = { (f16)T[kq][n], (f16)T[kq + 1][n], (f16)T[kq + 2][n], (f16)T[kq + 3][n] };
    *(f16x4*)(Dt + (size_t)(n0 + n) * K + k0 + kq) = o;
}

// ---------------------------------------------------------------------------
// MFMA f16 GEMM: C[M,N] = A[M,K] @ Bt[N,K]^T + bias[N]. A,Bt f16; bias f32.
// 128x128 tile, BK=32, 4 waves (2x2 of 64x64), 16x16x32 MFMA, 4x4 tiles/wave.
// 2-phase pipeline: LDS double-buffer, stage(t+1) issued BEFORE compute(t),
// single __syncthreads() (vmcnt drain) per K-step -> load latency hidden
// under the 16 MFMAs even at 1 block/CU (N=512 grids).
// VTOUT=1: write V-projection output directly in vt[bh][d][s] f16 layout
// (the GEMM epilogue already holds 4 consecutive s at fixed d per acc reg).
// ---------------------------------------------------------------------------
template <int RELU, int OUT16, int VTOUT>
__global__ __launch_bounds__(256) void k_gemm(
    const f16* __restrict__ A, const f16* __restrict__ Bt,
    const float* __restrict__ bias, float* __restrict__ C, f16* __restrict__ Ch,
    int M, int N, int K)
{
    __shared__ f16 As[2 * 128 * 32];
    __shared__ f16 Bs[2 * 128 * 32];
    int tid = threadIdx.x;
    int w = tid >> 6, lane = tid & 63;
    int ln = lane & 15, rg = lane >> 4;
    int wr = w >> 1, wc = w & 1;
    int m0 = blockIdx.y * 128, n0 = blockIdx.x * 128;

    int s0 = tid, s1 = 256 + tid;
    int r0s = s0 >> 2, c0s = ((s0 & 3) ^ ((s0 >> 3) & 3));
    int r1s = s1 >> 2, c1s = ((s1 & 3) ^ ((s1 >> 3) & 3));

    const f16* a0 = A + (size_t)(m0 + r0s) * K + c0s * 8;
    const f16* a1 = A + (size_t)(m0 + r1s) * K + c1s * 8;
    const f16* b0 = Bt + (size_t)(n0 + r0s) * K + c0s * 8;
    const f16* b1 = Bt + (size_t)(n0 + r1s) * K + c1s * 8;

    int cc8 = (rg ^ ((ln >> 1) & 3)) * 8;

    f32x4 acc[4][4] = {};

    int nk = K >> 5;

    // prologue: stage K-step 0 into buffer 0
    {
        f16* lA = As + (size_t)(w * 64) * 8;
        f16* lB = Bs + (size_t)(w * 64) * 8;
        GLDS16(a0, lA);
        GLDS16(a1, lA + 2048);
        GLDS16(b0, lB);
        GLDS16(b1, lB + 2048);
    }
    __syncthreads();   // vmcnt(0) drain: buf0 ready

    int cur = 0;
    for (int t = 0; t < nk; ++t) {
        // issue next-tile loads FIRST (overlap with compute below)
        if (t + 1 < nk) {
            int kt = (t + 1) << 5;
            int nb = cur ^ 1;
            f16* lA = As + nb * 4096 + (size_t)(w * 64) * 8;
            f16* lB = Bs + nb * 4096 + (size_t)(w * 64) * 8;
            GLDS16(a0 + kt, lA);
            GLDS16(a1 + kt, lA + 2048);
            GLDS16(b0 + kt, lB);
            GLDS16(b1 + kt, lB + 2048);
        }

        const f16* Ab = As + cur * 4096;
        const f16* Bb = Bs + cur * 4096;
        f16x8 af[4], bf[4];
#pragma unroll
        for (int i = 0; i < 4; ++i) {
            int m = wr * 64 + i * 16 + ln;
            af[i] = *(const f16x8*)(Ab + m * 32 + cc8);
            int nn = wc * 64 + i * 16 + ln;
            bf[i] = *(const f16x8*)(Bb + nn * 32 + cc8);
        }
#pragma unroll
        for (int i = 0; i < 4; ++i)
#pragma unroll
            for (int j = 0; j < 4; ++j)
                acc[i][j] = __builtin_amdgcn_mfma_f32_16x16x32_f16(af[i], bf[j], acc[i][j], 0, 0, 0);

        __syncthreads();   // drains vmcnt(0): next buffer staged, reads done
        cur ^= 1;
    }

#pragma unroll
    for (int j = 0; j < 4; ++j) {
        int col = n0 + wc * 64 + j * 16 + ln;
        float bj = bias[col];
#pragma unroll
        for (int i = 0; i < 4; ++i) {
            int rb = m0 + wr * 64 + i * 16 + rg * 4;
            if (VTOUT) {
                // vt[((b*8+h)*64 + dk)*512 + s], s = 4 consecutive rows
                int bq = rb >> 9, s = rb & 511;
                int hh = col >> 6, dk = col & 63;
                f16x4 o;
#pragma unroll
                for (int r = 0; r < 4; ++r) o[r] = (f16)(acc[i][j][r] + bj);
                *(f16x4*)(Ch + (((size_t)(bq * 8 + hh) * 64 + dk) << 9) + s) = o;
            } else {
#pragma unroll
                for (int r = 0; r < 4; ++r) {
                    float v = acc[i][j][r] + bj;
                    if (RELU) v = fmaxf(v, 0.f);
                    if (OUT16) Ch[(size_t)(rb + r) * N + col] = (f16)v;
                    else       C [(size_t)(rb + r) * N + col] = v;
                }
            }
        }
    }
}

// ---------------------------------------------------------------------------
// AKT attention, MFMA. One block per (b, h, 16-row i-tile), 4 waves.
// Phase 1: S = Q K^T via mfma 16x16x32_f16, frags direct from global (qh),
//          j-tiles round-robin across waves, C-frags -> LDS Sc f32.
// Phase 2: per-row softmax/cumsum/decay/softmax (wave w owns rows w*4..+3),
//          writes P f16 into XOR-swizzled Ph.
// Phase 3: O = P V via mfma; wave w owns d-block nb=w; A from Ph (swizzled),
//          B from vt global. Two barriers total.
// ---------------------------------------------------------------------------
__global__ __launch_bounds__(256) void k_attn(
    const f16* __restrict__ Qh, const f16* __restrict__ VT,
    f16* __restrict__ O, const float* __restrict__ gam, int maskflag)
{
    __shared__ float Sc[16][516];
    __shared__ f16 Ph[16 * 512];

    int tid = threadIdx.x;
    int w = tid >> 6, lane = tid & 63;
    int ln = lane & 15, rg = lane >> 4;
    int tile = blockIdx.x & 31;
    int bh = blockIdx.x >> 5;
    int b = bh >> 3, h = bh & 7;
    int i0 = tile * 16;
    int jtc = (tile >> 2) + 1;

    const f16* Qbase = Qh + ((size_t)b * Sl) * Dm + h * DKh;

    float gm = gam[h];
    float g = -((gm > 20.f) ? gm : log1pf(__expf(gm)));   // -softplus(gamma)

    // A-frags: Q rows i0..i0+15 (A[m=ln][k=rg*8+t]), reused across j-tiles
    f16x8 aq0 = *(const f16x8*)(Qbase + (size_t)(i0 + ln) * Dm + rg * 8);
    f16x8 aq1 = *(const f16x8*)(Qbase + (size_t)(i0 + ln) * Dm + 32 + rg * 8);

    // ---- Phase 1: scores ------------------------------------------------
    for (int jt = w; jt < jtc; jt += 4) {
        int j0 = jt * 64;
#pragma unroll
        for (int nb = 0; nb < 4; ++nb) {
            const f16* kb = Qbase + (size_t)(j0 + nb * 16 + ln) * Dm + rg * 8;
            f16x8 b0 = *(const f16x8*)(kb);
            f16x8 b1 = *(const f16x8*)(kb + 32);
            f32x4 c = {};
            c = __builtin_amdgcn_mfma_f32_16x16x32_f16(aq0, b0, c, 0, 0, 0);
            c = __builtin_amdgcn_mfma_f32_16x16x32_f16(aq1, b1, c, 0, 0, 0);
#pragma unroll
            for (int r = 0; r < 4; ++r)
                Sc[rg * 4 + r][j0 + nb * 16 + ln] = c[r];
        }
    }
    __syncthreads();

    // ---- Phase 2: softmax -> cumsum -> decay -> softmax -----------------
    for (int q = 0; q < 4; ++q) {
        int r = w * 4 + q;
        int i = i0 + r;
        int jmax = maskflag ? i : (i - 1);

        float4 s0 = *(float4*)&Sc[r][lane * 8];
        float4 s1 = *(float4*)&Sc[r][lane * 8 + 4];
        float s[8] = {s0.x, s0.y, s0.z, s0.w, s1.x, s1.y, s1.z, s1.w};
#pragma unroll
        for (int k = 0; k < 8; ++k) {
            int j = lane * 8 + k;
            s[k] = (j <= jmax) ? s[k] * 0.125f : NEGV;
        }
        float m = s[0];
#pragma unroll
        for (int k = 1; k < 8; ++k) m = fmaxf(m, s[k]);
#pragma unroll
        for (int off = 32; off >= 1; off >>= 1) m = fmaxf(m, __shfl_xor(m, off));
        float p[8], Z = 0.f;
#pragma unroll
        for (int k = 0; k < 8; ++k) { p[k] = __expf(s[k] - m); Z += p[k]; }
#pragma unroll
        for (int off = 32; off >= 1; off >>= 1) Z += __shfl_xor(Z, off);
        float inv = 1.f / Z;

        float cs[8], run = 0.f;
#pragma unroll
        for (int k = 0; k < 8; ++k) {
            int j = lane * 8 + k;
            float pm = (j <= jmax) ? p[k] * inv : 0.f;
            run += pm;
            cs[k] = run;
        }
        float sl = run;
#pragma unroll
        for (int off = 1; off < 64; off <<= 1) {
            float nv = __shfl_up(sl, off);
            if (lane >= off) sl += nv;
        }
        float excl = sl - run;
        float tot = __shfl(sl, 63);

#pragma unroll
        for (int k = 0; k < 8; ++k) {
            int j = lane * 8 + k;
            float dc = excl + cs[k];
            float pos = fabsf((float)(i - j));
            float dd = fmaxf((tot - dc) * pos, 0.f);
            float te = __expf(sqrtf(dd) * g);
            te = fminf(fmaxf(te, 1e-5f), 1e5f);
            s[k] = (j <= jmax) ? s[k] * te : NEGV;
        }

        m = s[0];
#pragma unroll
        for (int k = 1; k < 8; ++k) m = fmaxf(m, s[k]);
#pragma unroll
        for (int off = 32; off >= 1; off >>= 1) m = fmaxf(m, __shfl_xor(m, off));
        Z = 0.f;
#pragma unroll
        for (int k = 0; k < 8; ++k) { p[k] = __expf(s[k] - m); Z += p[k]; }
#pragma unroll
        for (int off = 32; off >= 1; off >>= 1) Z += __shfl_xor(Z, off);
        inv = 1.f / Z;

        int zp = (maskflag == 0) && (i == 0);
        float a[8];
#pragma unroll
        for (int k = 0; k < 8; ++k) a[k] = zp ? 0.f : p[k] * inv;

        // write P f16, chunk c=lane, slot low3 ^= (r&7)  -> conflict-free
        int slot = (lane & ~7) | ((lane & 7) ^ (r & 7));
        f16x8 o8 = { (f16)a[0], (f16)a[1], (f16)a[2], (f16)a[3],
                     (f16)a[4], (f16)a[5], (f16)a[6], (f16)a[7] };
        *(f16x8*)(Ph + r * 512 + slot * 8) = o8;
    }
    __syncthreads();

    // ---- Phase 3: O = P @ V, wave w owns d-block nb=w -------------------
    f32x4 oa = {};
    for (int jt = 0; jt < jtc; ++jt) {
        int j0 = jt * 64;
#pragma unroll
        for (int ks = 0; ks < 2; ++ks) {
            int c = jt * 8 + ks * 4 + rg;
            int slot = (c & ~7) | ((c & 7) ^ (ln & 7));
            f16x8 ap = *(const f16x8*)(Ph + ln * 512 + slot * 8);
            const f16* vb_ = VT + ((size_t)bh * 64 + w * 16 + ln) * 512
                             + j0 + ks * 32 + rg * 8;
            f16x8 bv = *(const f16x8*)vb_;
            oa = __builtin_amdgcn_mfma_f32_16x16x32_f16(ap, bv, oa, 0, 0, 0);
        }
    }
    f16* ob = O + ((size_t)b * Sl + i0 + rg * 4) * Dm + h * DKh + w * 16 + ln;
#pragma unroll
    for (int r = 0; r < 4; ++r)
        ob[(size_t)r * Dm] = (f16)oa[r];
}

// ---------------------------------------------------------------------------
// Residual + LayerNorm: Out = LN(Xn + Rr)*g + b, dual f32+f16 output.
// ---------------------------------------------------------------------------
__global__ __launch_bounds__(256) void k_ln(
    const float* __restrict__ Xn, const float* __restrict__ Rr,
    const float* __restrict__ gw, const float* __restrict__ bw,
    float* __restrict__ Out, f16* __restrict__ Outh)
{
    int tid = threadIdx.x;
    int w = tid >> 6, lane = tid & 63;
    int row = blockIdx.x * 4 + w;
    const float* xr = Xn + (size_t)row * Dm;
    const float* rr = Rr + (size_t)row * Dm;
    float v[8], sum = 0.f;
#pragma unroll
    for (int r = 0; r < 8; ++r) {
        int c = lane + r * 64;
        v[r] = xr[c] + rr[c];
        sum += v[r];
    }
#pragma unroll
    for (int off = 32; off >= 1; off >>= 1) sum += __shfl_xor(sum, off);
    float mu = sum * (1.f / 512.f);
    float var = 0.f;
#pragma unroll
    for (int r = 0; r < 8; ++r) { float d = v[r] - mu; var += d * d; }
#pragma unroll
    for (int off = 32; off >= 1; off >>= 1) var += __shfl_xor(var, off);
    float rs = rsqrtf(var * (1.f / 512.f) + 1e-5f);
    float* orow = Out + (size_t)row * Dm;
    f16* ohrow = Outh + (size_t)row * Dm;
#pragma unroll
    for (int r = 0; r < 8; ++r) {
        int c = lane + r * 64;
        float val = (v[r] - mu) * rs * gw[c] + bw[c];
        orow[c] = val;
        ohrow[c] = (f16)val;
    }
}

// ---------------------------------------------------------------------------
extern "C" void kernel_launch(void* const* d_in, const int* in_sizes, int n_in,
                              void* d_out, int out_size, void* d_ws, size_t ws_size,
                              hipStream_t stream)
{
    const float* q_emb  = (const float*)d_in[0];
    const float* qa_emb = (const float*)d_in[1];
    const float* Wk  = (const float*)d_in[3];
    const float* bk  = (const float*)d_in[4];
    const float* Wv  = (const float*)d_in[5];
    const float* bv  = (const float*)d_in[6];
    const float* Wo  = (const float*)d_in[7];
    const float* bo  = (const float*)d_in[8];
    const float* gam = (const float*)d_in[9];
    const float* l1g = (const float*)d_in[10];
    const float* l1b = (const float*)d_in[11];
    const float* W1  = (const float*)d_in[12];
    const float* b1  = (const float*)d_in[13];
    const float* W2  = (const float*)d_in[14];
    const float* b2  = (const float*)d_in[15];
    const float* l2g = (const float*)d_in[16];
    const float* l2b = (const float*)d_in[17];
    float* outp = (float*)d_out;

    const size_t NE  = (size_t)MROWS * Dm;    // 4194304
    const size_t WDD = (size_t)Dm * Dm;
    const size_t WDF = (size_t)Dm * DFFn;

    float* xbuf = (float*)d_ws;               // NE f32
    float* ybuf = xbuf + NE;                  // NE f32
    float* t2   = ybuf + NE;                  // NE f32 (LN input temp)
    f16* xh  = (f16*)(t2 + NE);               // NE
    f16* yh  = xh + NE;                       // NE
    f16* R   = yh + NE;                       // 4*NE f16 region
    f16* qh  = R;                             // q(=k) heads f16
    f16* vt  = R + 2 * NE;                    // v transposed per head (fused)
    f16* t1h = R + 3 * NE;                    // attention output f16
    f16* fbh = R;                             // FFN hidden (aliases R, 4*NE)
    f16* wkh = R + 4 * NE;                    // weights f16
    f16* wvh = wkh + 6 * WDD;
    f16* woh = wvh + 6 * WDD;
    f16* w1h = woh + 6 * WDD;                 // slots 0,1,3,5
    f16* w2h = w1h + 4 * WDF;

    // ---- per-call weight convert+transpose (f32 [K,N] -> f16 [N,K]) ----
    k_wconv<<<dim3(Dm / 32, Dm / 32, 6), 256, 0, stream>>>(Wk, wkh, Dm, Dm, 0);
    k_wconv<<<dim3(Dm / 32, Dm / 32, 6), 256, 0, stream>>>(Wv, wvh, Dm, Dm, 0);
    k_wconv<<<dim3(Dm / 32, Dm / 32, 6), 256, 0, stream>>>(Wo, woh, Dm, Dm, 0);
    k_wconv<<<dim3(DFFn / 32, Dm / 32, 4), 256, 0, stream>>>(W1, w1h, Dm, DFFn, 1);
    k_wconv<<<dim3(Dm / 32, DFFn / 32, 4), 256, 0, stream>>>(W2, w2h, DFFn, Dm, 1);

    const int n = (int)NE;
    k_copy2<<<n / 256, 256, 0, stream>>>(q_emb,  xbuf, xh, n);
    k_copy2<<<n / 256, 256, 0, stream>>>(qa_emb, ybuf, yh, n);

    auto gemm16 = [&](const f16* A, const f16* Bt, const float* bias, f16* C,
                      int M, int N, int K) {
        k_gemm<0, 1, 0><<<dim3(N / 128, M / 128), 256, 0, stream>>>(A, Bt, bias, nullptr, C, M, N, K);
    };
    auto gemm32 = [&](const f16* A, const f16* Bt, const float* bias, float* C,
                      int M, int N, int K) {
        k_gemm<0, 0, 0><<<dim3(N / 128, M / 128), 256, 0, stream>>>(A, Bt, bias, C, nullptr, M, N, K);
    };
    auto gemmvt = [&](const f16* A, const f16* Bt, const float* bias, f16* C) {
        k_gemm<0, 1, 1><<<dim3(Dm / 128, MROWS / 128), 256, 0, stream>>>(A, Bt, bias, nullptr, C, MROWS, Dm, Dm);
    };

    // finalOut: if non-null, the LAST LayerNorm's f32 result goes there
    // (the f32 residual stream is dead afterwards; f16 mirror still written).
    auto layer = [&](int l, int maskflag, float* Xq, f16* Xqh, f16* Xvh,
                     bool apply_pos, float* finalOut) {
        gemm16(Xqh, wkh + (size_t)l * WDD, bk + l * Dm, qh, MROWS, Dm, Dm);
        gemmvt(Xvh, wvh + (size_t)l * WDD, bv + l * Dm, vt);
        k_attn<<<Bsz * Hn * 32, 256, 0, stream>>>(qh, vt, t1h, gam + l * Hn, maskflag);
        gemm32(t1h, woh + (size_t)l * WDD, bo + l * Dm, t2, MROWS, Dm, Dm);
        if (apply_pos) {
            k_ln<<<MROWS / 4, 256, 0, stream>>>(t2, Xq, l1g + l * Dm, l1b + l * Dm, Xq, Xqh);
            int sl = (l < 2) ? l : ((l + 1) >> 1);
            k_gemm<1, 1, 0><<<dim3(DFFn / 128, MROWS / 128), 256, 0, stream>>>(
                Xqh, w1h + (size_t)sl * WDF, b1 + l * DFFn, nullptr, fbh, MROWS, DFFn, Dm);
            k_gemm<0, 0, 0><<<dim3(Dm / 128, MROWS / 128), 256, 0, stream>>>(
                fbh, w2h + (size_t)sl * WDF, b2 + l * Dm, t2, nullptr, MROWS, Dm, DFFn);
            k_ln<<<MROWS / 4, 256, 0, stream>>>(t2, Xq, l2g + l * Dm, l2b + l * Dm,
                                                finalOut ? finalOut : Xq, Xqh);
        } else {
            k_ln<<<MROWS / 4, 256, 0, stream>>>(t2, Xq, l1g + l * Dm, l1b + l * Dm,
                                                finalOut ? finalOut : Xq, Xqh);
        }
    };

    const size_t NEo = NE;
    // blocks_1: self-attn on y, mask=1, FFN. Layer 1 is y's final write -> out+NE.
    layer(0, 1, ybuf, yh, yh, true, nullptr);
    layer(1, 1, ybuf, yh, yh, true, outp + NEo);
    // blocks_2: (mask=1, no FFN) then (mask=0, values=y, FFN), twice.
    // Layer 5 is x's final write -> out.
    layer(2, 1, xbuf, xh, xh, false, nullptr);
    layer(3, 0, xbuf, xh, yh, true, nullptr);
    layer(4, 1, xbuf, xh, xh, false, nullptr);
    layer(5, 0, xbuf, xh, yh, true, outp);
}